// Round 5
// baseline (51.932 us; speedup 1.0000x reference)
//
#include <hip/hip_runtime.h>

#define K 5
#define N_ 8
#define C_ 256
#define H_ 64
#define W_ 64
#define HW (H_ * W_)
#define HO 128
#define WO 128
#define HOWO (HO * WO)
#define HB 8              // base rows per block
#define WB 32             // base cols per block
#define UC 8              // channels per block (single group)
#define LDS_R (HB + K - 1)        // 12
#define LDS_C (WB + K - 1)        // 36
#define POS (LDS_R * LDS_C)       // 432

typedef __attribute__((ext_vector_type(2))) float f2;

__global__ __launch_bounds__(256)
void carafe_flat_kernel(const float* __restrict__ feat,
                        const float* __restrict__ mask,
                        float* __restrict__ out) {
    const int wt = blockIdx.x;       // 0..1
    const int ht = blockIdx.y;       // 0..7
    const int zc = blockIdx.z;       // 0..255  (n*32 + chunk)
    const int n  = zc >> 5;
    const int c0 = (zc & 31) * UC;
    const int h0 = ht * HB;
    const int w0 = wt * WB;

    const int tid = threadIdx.x;
    const int r   = tid >> 5;        // 0..7  base row in tile
    const int c   = tid & 31;        // 0..31 base col in tile
    const int hb  = h0 + r;
    const int wb  = w0 + c;

    // Staging geometry: halo positions tid and tid+256 (if < POS).
    int off0, off1;
    bool v0, v1, has1;
    {
        int p  = tid;
        int rr = p / LDS_C, cc = p - rr * LDS_C;
        int hs = h0 - 2 + rr, ws = w0 - 2 + cc;
        v0   = (hs >= 0 && hs < H_ && ws >= 0 && ws < W_);
        off0 = hs * W_ + ws;
    }
    has1 = (tid + 256) < POS;
    {
        int p  = tid + 256;
        int rr = p / LDS_C, cc = p - rr * LDS_C;
        int hs = h0 - 2 + rr, ws = w0 - 2 + cc;
        v1   = has1 && (hs >= 0 && hs < H_ && ws >= 0 && ws < W_);
        off1 = hs * W_ + ws;
    }

    // Channel-interleaved halo tile: [slab of 4ch][pos] as float4. 13.8 KB.
    __shared__ float4 lds[2][POS];

    const float* fbase = feat + (size_t)n * C_ * HW + (size_t)c0 * HW;

    // ---- stage 8 channels into LDS (single buffer, one sync) ----
    {
        float s0[UC], s1[UC];
        #pragma unroll
        for (int u = 0; u < UC; ++u) s0[u] = v0 ? fbase[u * HW + off0] : 0.f;
        #pragma unroll
        for (int u = 0; u < UC; ++u) s1[u] = v1 ? fbase[u * HW + off1] : 0.f;
        lds[0][tid] = make_float4(s0[0], s0[1], s0[2], s0[3]);
        lds[1][tid] = make_float4(s0[4], s0[5], s0[6], s0[7]);
        if (has1) {
            lds[0][tid + 256] = make_float4(s1[0], s1[1], s1[2], s1[3]);
            lds[1][tid + 256] = make_float4(s1[4], s1[5], s1[6], s1[7]);
        }
    }
    __syncthreads();

    // ---- compute the 2x2 quad for 8 channels ----
    // Masks loaded per-tap (f2 over b), interleaved with FMAs: short live
    // ranges keep VGPR low; L2/L3 serves re-reads across channel chunks.
    const f2* mb = (const f2*)(mask + (size_t)n * (K * K) * HOWO
                                    + (size_t)(2 * hb) * WO + 2 * wb);
    const int rbase = r * LDS_C + c;

    f2 a0[UC], a1[UC];   // [channel] x {a=0,a=1}, each f2 over b
    #pragma unroll
    for (int u = 0; u < UC; ++u) { a0[u] = (f2)0.f; a1[u] = (f2)0.f; }

    #pragma unroll
    for (int ki = 0; ki < K; ++ki) {
        #pragma unroll
        for (int kj = 0; kj < K; ++kj) {
            const int i = ki * K + kj;
            f2 m0 = mb[(size_t)i * (HOWO / 2)];            // output row a=0
            f2 m1 = mb[(size_t)i * (HOWO / 2) + WO / 2];   // output row a=1
            float4 fA = lds[0][rbase + ki * LDS_C + kj];   // ch 0..3
            float4 fB = lds[1][rbase + ki * LDS_C + kj];   // ch 4..7
            a0[0] += fA.x * m0;  a1[0] += fA.x * m1;
            a0[1] += fA.y * m0;  a1[1] += fA.y * m1;
            a0[2] += fA.z * m0;  a1[2] += fA.z * m1;
            a0[3] += fA.w * m0;  a1[3] += fA.w * m1;
            a0[4] += fB.x * m0;  a1[4] += fB.x * m1;
            a0[5] += fB.y * m0;  a1[5] += fB.y * m1;
            a0[6] += fB.z * m0;  a1[6] += fB.z * m1;
            a0[7] += fB.w * m0;  a1[7] += fB.w * m1;
        }
    }

    float* obase = out + (size_t)n * C_ * HOWO + (size_t)c0 * HOWO
                       + (size_t)(2 * hb) * WO + 2 * wb;
    #pragma unroll
    for (int u = 0; u < UC; ++u) {
        f2* op = (f2*)(obase + (size_t)u * HOWO);
        __builtin_nontemporal_store(a0[u], op);            // row 2hb
        __builtin_nontemporal_store(a1[u], op + WO / 2);   // row 2hb+1
    }
}

extern "C" void kernel_launch(void* const* d_in, const int* in_sizes, int n_in,
                              void* d_out, int out_size, void* d_ws, size_t ws_size,
                              hipStream_t stream) {
    const float* feat = (const float*)d_in[0];
    const float* mask = (const float*)d_in[1];
    float* out = (float*)d_out;

    dim3 grid(W_ / WB, H_ / HB, N_ * (C_ / UC));  // (2, 8, 256) = 4096 blocks
    dim3 block(256);
    carafe_flat_kernel<<<grid, block, 0, stream>>>(feat, mask, out);
}

// Round 6
// 46.998 us; speedup vs baseline: 1.1050x; 1.1050x over previous
//
#include <hip/hip_runtime.h>

#define K 5
#define N_ 8
#define C_ 256
#define H_ 64
#define W_ 64
#define HW (H_ * W_)
#define HO 128
#define WO 128
#define HOWO (HO * WO)
#define HB 8              // base rows per block (2 per wave)
#define WB 32             // base cols per block
#define CCHUNK 32         // channels per block
#define UC 4              // channels per group (1 float4 slab)
#define NG (CCHUNK / UC)          // 8 groups
#define HALO_R 6                  // per-wave halo rows (2 base rows + 4)
#define LDS_C (WB + K - 1)        // 36
#define WPOS (HALO_R * LDS_C)     // 216 positions per wave

typedef __attribute__((ext_vector_type(2))) float f2;

__global__ __launch_bounds__(256)
void carafe_wave_kernel(const float* __restrict__ feat,
                        const float* __restrict__ mask,
                        float* __restrict__ out) {
    const int wt = blockIdx.x;       // 0..1
    const int ht = blockIdx.y;       // 0..7
    const int zc = blockIdx.z;       // 0..63 (n*8 + chunk)
    const int n  = zc >> 3;
    const int c0 = (zc & 7) * CCHUNK;
    const int h0 = ht * HB;
    const int w0 = wt * WB;

    const int tid  = threadIdx.x;
    const int wave = tid >> 6;       // 0..3, owns base rows 2w,2w+1
    const int lane = tid & 63;
    const int r    = tid >> 5;       // 0..7 base row in tile
    const int c    = tid & 31;       // 0..31 base col in tile
    const int hb   = h0 + r;
    const int wb   = w0 + c;

    // Channel-invariant masks for this thread's 2x2 quad (f2 over b).
    f2 m0[K * K], m1[K * K];
    const f2* mb = (const f2*)(mask + (size_t)n * (K * K) * HOWO
                                    + (size_t)(2 * hb) * WO + 2 * wb);
    #pragma unroll
    for (int i = 0; i < K * K; ++i) {
        m0[i] = mb[(size_t)i * (HOWO / 2)];            // a = 0
        m1[i] = mb[(size_t)i * (HOWO / 2) + WO / 2];   // a = 1
    }

    // Wave-private halo: rows h0+2*wave-2 .. +3, cols w0-2 .. w0+33.
    int  off[4];
    bool val[4];
    #pragma unroll
    for (int i = 0; i < 4; ++i) {
        int p  = i * 64 + lane;
        int rr = p / LDS_C, cc = p - rr * LDS_C;
        int hs = h0 + 2 * wave - 2 + rr;
        int ws = w0 - 2 + cc;
        val[i] = (p < WPOS) && (hs >= 0) && (hs < H_) && (ws >= 0) && (ws < W_);
        off[i] = hs * W_ + ws;
    }

    // Per-wave double-buffered channel-interleaved tile. 27648 B.
    __shared__ float4 lds[4][2][WPOS];

    const float* fbase = feat + (size_t)n * C_ * HW;

    float s[4][UC];
    auto load_group = [&](int cb) {
        const float* fp = fbase + (size_t)cb * HW;
        #pragma unroll
        for (int i = 0; i < 4; ++i)
            #pragma unroll
            for (int u = 0; u < UC; ++u)
                s[i][u] = val[i] ? fp[u * HW + off[i]] : 0.f;
    };
    auto write_group = [&](int buf) {
        #pragma unroll
        for (int i = 0; i < 4; ++i) {
            int p = i * 64 + lane;
            if (p < WPOS)
                lds[wave][buf][p] = make_float4(s[i][0], s[i][1], s[i][2], s[i][3]);
        }
    };

    // Prologue (wave-local, no barrier).
    load_group(c0);
    write_group(0);

    float* obase = out + (size_t)n * C_ * HOWO + (size_t)(2 * hb) * WO + 2 * wb;
    const int rbase = (r & 1) * LDS_C + c;   // tap (0,0) in wave halo

    for (int g = 0; g < NG; ++g) {
        const int buf = g & 1;

        // T14: issue next group's global loads first (HBM latency hides
        // under this group's compute).
        if (g + 1 < NG) load_group(c0 + (g + 1) * UC);

        const float4* Ls = &lds[wave][buf][rbase];
        f2 a0[UC], a1[UC];
        #pragma unroll
        for (int u = 0; u < UC; ++u) { a0[u] = (f2)0.f; a1[u] = (f2)0.f; }
        #pragma unroll
        for (int ki = 0; ki < K; ++ki) {
            #pragma unroll
            for (int kj = 0; kj < K; ++kj) {
                float4 f  = Ls[ki * LDS_C + kj];   // 1 ds_read_b128
                f2 w0m = m0[ki * K + kj];
                f2 w1m = m1[ki * K + kj];
                a0[0] += f.x * w0m;  a1[0] += f.x * w1m;
                a0[1] += f.y * w0m;  a1[1] += f.y * w1m;
                a0[2] += f.z * w0m;  a1[2] += f.z * w1m;
                a0[3] += f.w * w0m;  a1[3] += f.w * w1m;
            }
        }

        // Write next buffer (same-wave vmcnt/lgkmcnt ordering; no barrier).
        if (g + 1 < NG) write_group(buf ^ 1);

        // Fire-and-forget stores last: nothing ever waits on them.
        float* oc = obase + (size_t)(c0 + g * UC) * HOWO;
        #pragma unroll
        for (int u = 0; u < UC; ++u) {
            f2* op = (f2*)(oc + (size_t)u * HOWO);
            __builtin_nontemporal_store(a0[u], op);            // row 2hb
            __builtin_nontemporal_store(a1[u], op + WO / 2);   // row 2hb+1
        }
    }
}

extern "C" void kernel_launch(void* const* d_in, const int* in_sizes, int n_in,
                              void* d_out, int out_size, void* d_ws, size_t ws_size,
                              hipStream_t stream) {
    const float* feat = (const float*)d_in[0];
    const float* mask = (const float*)d_in[1];
    float* out = (float*)d_out;

    dim3 grid(W_ / WB, H_ / HB, N_ * (C_ / CCHUNK));  // (2, 8, 64)
    dim3 block(256);
    carafe_wave_kernel<<<grid, block, 0, stream>>>(feat, mask, out);
}